// Round 1
// baseline (1010.379 us; speedup 1.0000x reference)
//
#include <hip/hip_runtime.h>
#include <hip/hip_bf16.h>

// Problem constants
#define BB 2
#define LL 1024
#define DD 1024
#define DI 2048
#define SS 16
#define KK 4
#define RR 64
#define MROWS (BB*LL)   // 2048

// ---------------------------------------------------------------------------
// Shared fp32 SGEMM: C[M,N] = A[M,K] * B[N,K]^T   (both row-major over K)
// 128x128 tile, BK=16, 256 threads, 8x8 micro-tile.
// LDS stored transposed As[k][m], Bs[k][n] for float4 fragment reads.
// ---------------------------------------------------------------------------
#define BM 128
#define BN 128
#define BK 16

__global__ __launch_bounds__(256) void sgemm_bt(const float* __restrict__ A,
                                                const float* __restrict__ B,
                                                float* __restrict__ C,
                                                int M, int N, int K) {
    __shared__ float As[BK][BM + 4];
    __shared__ float Bs[BK][BN + 4];
    const int tid = threadIdx.x;
    const int bm = blockIdx.y * BM;
    const int bn = blockIdx.x * BN;
    const int tx = tid & 15;        // n-fragment selector
    const int ty = tid >> 4;        // m-fragment selector
    const int lrow = tid >> 2;      // 0..63 loader row
    const int lcol = (tid & 3) * 4; // 0,4,8,12 loader k-offset

    float acc[8][8];
#pragma unroll
    for (int i = 0; i < 8; ++i)
#pragma unroll
        for (int j = 0; j < 8; ++j) acc[i][j] = 0.f;

    for (int kt = 0; kt < K; kt += BK) {
#pragma unroll
        for (int i = 0; i < 2; ++i) {
            const int r = lrow + i * 64;
            float4 va = *(const float4*)&A[(size_t)(bm + r) * K + kt + lcol];
            As[lcol + 0][r] = va.x; As[lcol + 1][r] = va.y;
            As[lcol + 2][r] = va.z; As[lcol + 3][r] = va.w;
            float4 vb = *(const float4*)&B[(size_t)(bn + r) * K + kt + lcol];
            Bs[lcol + 0][r] = vb.x; Bs[lcol + 1][r] = vb.y;
            Bs[lcol + 2][r] = vb.z; Bs[lcol + 3][r] = vb.w;
        }
        __syncthreads();
#pragma unroll
        for (int k = 0; k < BK; ++k) {
            float4 a0 = *(const float4*)&As[k][ty * 4];
            float4 a1 = *(const float4*)&As[k][64 + ty * 4];
            float4 b0 = *(const float4*)&Bs[k][tx * 4];
            float4 b1 = *(const float4*)&Bs[k][64 + tx * 4];
            float av[8] = {a0.x, a0.y, a0.z, a0.w, a1.x, a1.y, a1.z, a1.w};
            float bv[8] = {b0.x, b0.y, b0.z, b0.w, b1.x, b1.y, b1.z, b1.w};
#pragma unroll
            for (int i = 0; i < 8; ++i)
#pragma unroll
                for (int j = 0; j < 8; ++j) acc[i][j] += av[i] * bv[j];
        }
        __syncthreads();
    }

#pragma unroll
    for (int i = 0; i < 8; ++i) {
        const int m = bm + ((i < 4) ? (ty * 4 + i) : (64 + ty * 4 + (i - 4)));
        float4 c0 = {acc[i][0], acc[i][1], acc[i][2], acc[i][3]};
        float4 c1 = {acc[i][4], acc[i][5], acc[i][6], acc[i][7]};
        *(float4*)&C[(size_t)m * N + bn + tx * 4] = c0;
        *(float4*)&C[(size_t)m * N + bn + 64 + tx * 4] = c1;
    }
}

// ---------------------------------------------------------------------------
// Depthwise causal conv (K=4) + bias + silu.  x is the first DI columns of xz.
// u stored (B, L, DI): coalesced over c, scan-friendly.
// ---------------------------------------------------------------------------
__global__ __launch_bounds__(256) void conv_silu(const float* __restrict__ xz,
                                                 const float* __restrict__ Wc,
                                                 const float* __restrict__ bc,
                                                 float* __restrict__ u) {
    const int c = blockIdx.x * 256 + threadIdx.x;   // 0..DI-1
    const int t = blockIdx.y;
    const int b = blockIdx.z;
    const float* xcol = xz + (size_t)b * LL * (2 * DI) + c;  // x[b][l][c] at l*(2*DI)
    const float w0 = Wc[c * 4 + 0], w1 = Wc[c * 4 + 1];
    const float w2 = Wc[c * 4 + 2], w3 = Wc[c * 4 + 3];
    float acc = bc[c];
    if (t >= 3) acc += xcol[(size_t)(t - 3) * (2 * DI)] * w0;
    if (t >= 2) acc += xcol[(size_t)(t - 2) * (2 * DI)] * w1;
    if (t >= 1) acc += xcol[(size_t)(t - 1) * (2 * DI)] * w2;
    acc += xcol[(size_t)t * (2 * DI)] * w3;
    const float sig = 1.f / (1.f + __expf(-acc));
    u[((size_t)b * LL + t) * DI + c] = acc * sig;
}

// ---------------------------------------------------------------------------
// proj[M,96] = u[M,DI] * W_x[96,DI]^T.  Tile 16(m) x 96(n), BKp=64.
// ---------------------------------------------------------------------------
__global__ __launch_bounds__(256) void proj_gemm(const float* __restrict__ U,
                                                 const float* __restrict__ Wx,
                                                 float* __restrict__ P) {
    const int BKp = 64;
    __shared__ float Us[16][BKp + 1];
    __shared__ float Ws[96][BKp + 1];
    const int tid = threadIdx.x;
    const int m0 = blockIdx.x * 16;
    const int tx = tid & 31;   // n base: n = tx + 32*j
    const int ty = tid >> 5;   // m pair: m = ty*2 + i
    float acc[2][3] = {{0.f, 0.f, 0.f}, {0.f, 0.f, 0.f}};

    for (int kt = 0; kt < DI; kt += BKp) {
        {
            const int r = tid >> 4;            // 0..15
            const int c4 = (tid & 15) << 2;    // 0..60
            float4 v = *(const float4*)&U[(size_t)(m0 + r) * DI + kt + c4];
            Us[r][c4] = v.x; Us[r][c4 + 1] = v.y; Us[r][c4 + 2] = v.z; Us[r][c4 + 3] = v.w;
        }
#pragma unroll
        for (int i = 0; i < 6; ++i) {
            const int idx = tid + i * 256;     // 0..1535
            const int r = idx >> 4;            // 0..95
            const int c4 = (idx & 15) << 2;
            float4 v = *(const float4*)&Wx[(size_t)r * DI + kt + c4];
            Ws[r][c4] = v.x; Ws[r][c4 + 1] = v.y; Ws[r][c4 + 2] = v.z; Ws[r][c4 + 3] = v.w;
        }
        __syncthreads();
#pragma unroll 8
        for (int k = 0; k < BKp; ++k) {
            const float um0 = Us[ty * 2][k];
            const float um1 = Us[ty * 2 + 1][k];
#pragma unroll
            for (int j = 0; j < 3; ++j) {
                const float w = Ws[tx + 32 * j][k];
                acc[0][j] += um0 * w;
                acc[1][j] += um1 * w;
            }
        }
        __syncthreads();
    }
#pragma unroll
    for (int i = 0; i < 2; ++i)
#pragma unroll
        for (int j = 0; j < 3; ++j)
            P[(size_t)(m0 + ty * 2 + i) * 96 + tx + 32 * j] = acc[i][j];
}

// ---------------------------------------------------------------------------
// dt[M,DI] = softplus(proj[:, :64] * W_dt[DI,64]^T + b_dt).  K=64 in registers.
// Block: 256 c-channels x 16 m-rows.
// ---------------------------------------------------------------------------
__global__ __launch_bounds__(256) void dt_gemm(const float* __restrict__ P,
                                               const float* __restrict__ Wdt,
                                               const float* __restrict__ bdt,
                                               float* __restrict__ dtb) {
    __shared__ float ps[16][68];
    const int tid = threadIdx.x;
    const int c = blockIdx.x * 256 + tid;
    const int m0 = blockIdx.y * 16;
    {
        const int r = tid >> 4;
        const int c4 = (tid & 15) << 2;
        float4 v = *(const float4*)&P[(size_t)(m0 + r) * 96 + c4];
        ps[r][c4] = v.x; ps[r][c4 + 1] = v.y; ps[r][c4 + 2] = v.z; ps[r][c4 + 3] = v.w;
    }
    float w[64];
#pragma unroll
    for (int r4 = 0; r4 < 64; r4 += 4) {
        float4 v = *(const float4*)&Wdt[(size_t)c * 64 + r4];
        w[r4] = v.x; w[r4 + 1] = v.y; w[r4 + 2] = v.z; w[r4 + 3] = v.w;
    }
    const float bd = bdt[c];
    __syncthreads();
#pragma unroll 4
    for (int m = 0; m < 16; ++m) {
        float acc = bd;
#pragma unroll
        for (int r4 = 0; r4 < 64; r4 += 4) {
            float4 p = *(const float4*)&ps[m][r4];
            acc += p.x * w[r4] + p.y * w[r4 + 1] + p.z * w[r4 + 2] + p.w * w[r4 + 3];
        }
        const float sp = (acc > 20.f) ? acc : __logf(1.f + __expf(acc));
        dtb[(size_t)(m0 + m) * DI + c] = sp;
    }
}

// ---------------------------------------------------------------------------
// Selective scan + silu(z) gating.  One lane per (b, c, s); 16-lane y-reduce.
// h_t = exp(dt*A)*h + dt*B_t*u_t ; y_t = sum_s C_t[s]*h ; gated = y*silu(z)
// ---------------------------------------------------------------------------
__global__ __launch_bounds__(256) void scan_gate(const float* __restrict__ dtb,
                                                 const float* __restrict__ u,
                                                 const float* __restrict__ proj,
                                                 const float* __restrict__ xz,
                                                 const float* __restrict__ A_log,
                                                 float* __restrict__ gated) {
    const int g = blockIdx.x * 256 + threadIdx.x;
    const int s = g & 15;
    const int c = (g >> 4) & (DI - 1);
    const int b = g >> 15;
    const float Aval = -expf(A_log[c * 16 + s]);

    const float* dtp = dtb + (size_t)b * LL * DI + c;
    const float* up  = u   + (size_t)b * LL * DI + c;
    const float* zp  = xz  + (size_t)b * LL * (2 * DI) + DI + c;
    const float* pp  = proj + (size_t)b * LL * 96;
    float* gp = gated + (size_t)b * LL * DI + c;

    float h = 0.f;
    float dtv = dtp[0];
    float uv  = up[0];
    float Bv  = pp[64 + s];
    float Cv  = pp[80 + s];
    float zv  = zp[0];

    for (int t = 0; t < LL; ++t) {
        // prefetch t+1 before the dependent chain
        float dtv_n = 0.f, uv_n = 0.f, Bv_n = 0.f, Cv_n = 0.f, zv_n = 0.f;
        if (t + 1 < LL) {
            dtv_n = dtp[(size_t)(t + 1) * DI];
            uv_n  = up[(size_t)(t + 1) * DI];
            Bv_n  = pp[(t + 1) * 96 + 64 + s];
            Cv_n  = pp[(t + 1) * 96 + 80 + s];
            zv_n  = zp[(size_t)(t + 1) * (2 * DI)];
        }
        const float ab = __expf(dtv * Aval);
        h = ab * h + (dtv * Bv) * uv;
        float y = Cv * h;
        y += __shfl_xor(y, 8);
        y += __shfl_xor(y, 4);
        y += __shfl_xor(y, 2);
        y += __shfl_xor(y, 1);
        if (s == 0) {
            const float sig = 1.f / (1.f + __expf(-zv));
            gp[(size_t)t * DI] = y * (zv * sig);
        }
        dtv = dtv_n; uv = uv_n; Bv = Bv_n; Cv = Cv_n; zv = zv_n;
    }
}

// ---------------------------------------------------------------------------
extern "C" void kernel_launch(void* const* d_in, const int* in_sizes, int n_in,
                              void* d_out, int out_size, void* d_ws, size_t ws_size,
                              hipStream_t stream) {
    const float* inputs = (const float*)d_in[0];
    const float* W_in   = (const float*)d_in[1];
    const float* W_conv = (const float*)d_in[2];
    const float* b_conv = (const float*)d_in[3];
    const float* W_x    = (const float*)d_in[4];
    const float* W_dt   = (const float*)d_in[5];
    const float* b_dt   = (const float*)d_in[6];
    const float* A_log  = (const float*)d_in[7];
    const float* W_out  = (const float*)d_in[8];
    float* out = (float*)d_out;

    float* ws = (float*)d_ws;
    float* xz    = ws;                          // 2048*4096 = 8388608
    float* u     = xz + (size_t)MROWS * 2 * DI; // 2048*2048 = 4194304
    float* proj  = u + (size_t)MROWS * DI;      // 2048*96   = 196608
    float* dtb   = proj + (size_t)MROWS * 96;   // 2048*2048 = 4194304
    float* gated = dtb + (size_t)MROWS * DI;    // 2048*2048 = 4194304

    // 1) xz = inputs @ W_in^T      (M=2048, N=4096, K=1024)
    sgemm_bt<<<dim3(2 * DI / BN, MROWS / BM), 256, 0, stream>>>(inputs, W_in, xz, MROWS, 2 * DI, DD);
    // 2) u = silu(conv(x) + b)     (B, L, DI)
    conv_silu<<<dim3(DI / 256, LL, BB), 256, 0, stream>>>(xz, W_conv, b_conv, u);
    // 3) proj = u @ W_x^T          (M=2048, N=96, K=2048)
    proj_gemm<<<dim3(MROWS / 16), 256, 0, stream>>>(u, W_x, proj);
    // 4) dt = softplus(proj[:,:64] @ W_dt^T + b_dt)
    dt_gemm<<<dim3(DI / 256, MROWS / 16), 256, 0, stream>>>(proj, W_dt, b_dt, dtb);
    // 5) scan + gate               (writes gated (B,L,DI))
    scan_gate<<<dim3(BB * DI * SS / 256), 256, 0, stream>>>(dtb, u, proj, xz, A_log, gated);
    // 6) out = gated @ W_out^T     (M=2048, N=1024, K=2048)
    sgemm_bt<<<dim3(DD / BN, MROWS / BM), 256, 0, stream>>>(gated, W_out, out, MROWS, DD, DI);
}

// Round 2
// 732.080 us; speedup vs baseline: 1.3801x; 1.3801x over previous
//
#include <hip/hip_runtime.h>
#include <hip/hip_bf16.h>

// Problem constants
#define BB 2
#define LL 1024
#define DD 1024
#define DI 2048
#define SS 16
#define KK 4
#define RR 64
#define MROWS (BB*LL)   // 2048

// ---------------------------------------------------------------------------
// fp32 SGEMM: C[M,N] = A[M,K] * B[N,K]^T   (A row-major over K)
// 128x128 tile, BK=16, 256 threads, 8x8 micro-tile.
// ---------------------------------------------------------------------------
#define BM 128
#define BN 128
#define BK 16

__global__ __launch_bounds__(256) void sgemm_bt(const float* __restrict__ A,
                                                const float* __restrict__ B,
                                                float* __restrict__ C,
                                                int M, int N, int K) {
    __shared__ float As[BK][BM + 4];
    __shared__ float Bs[BK][BN + 4];
    const int tid = threadIdx.x;
    const int bm = blockIdx.y * BM;
    const int bn = blockIdx.x * BN;
    const int tx = tid & 15;
    const int ty = tid >> 4;
    const int lrow = tid >> 2;
    const int lcol = (tid & 3) * 4;

    float acc[8][8];
#pragma unroll
    for (int i = 0; i < 8; ++i)
#pragma unroll
        for (int j = 0; j < 8; ++j) acc[i][j] = 0.f;

    for (int kt = 0; kt < K; kt += BK) {
#pragma unroll
        for (int i = 0; i < 2; ++i) {
            const int r = lrow + i * 64;
            float4 va = *(const float4*)&A[(size_t)(bm + r) * K + kt + lcol];
            As[lcol + 0][r] = va.x; As[lcol + 1][r] = va.y;
            As[lcol + 2][r] = va.z; As[lcol + 3][r] = va.w;
            float4 vb = *(const float4*)&B[(size_t)(bn + r) * K + kt + lcol];
            Bs[lcol + 0][r] = vb.x; Bs[lcol + 1][r] = vb.y;
            Bs[lcol + 2][r] = vb.z; Bs[lcol + 3][r] = vb.w;
        }
        __syncthreads();
#pragma unroll
        for (int k = 0; k < BK; ++k) {
            float4 a0 = *(const float4*)&As[k][ty * 4];
            float4 a1 = *(const float4*)&As[k][64 + ty * 4];
            float4 b0 = *(const float4*)&Bs[k][tx * 4];
            float4 b1 = *(const float4*)&Bs[k][64 + tx * 4];
            float av[8] = {a0.x, a0.y, a0.z, a0.w, a1.x, a1.y, a1.z, a1.w};
            float bv[8] = {b0.x, b0.y, b0.z, b0.w, b1.x, b1.y, b1.z, b1.w};
#pragma unroll
            for (int i = 0; i < 8; ++i)
#pragma unroll
                for (int j = 0; j < 8; ++j) acc[i][j] += av[i] * bv[j];
        }
        __syncthreads();
    }

#pragma unroll
    for (int i = 0; i < 8; ++i) {
        const int m = bm + ((i < 4) ? (ty * 4 + i) : (64 + ty * 4 + (i - 4)));
        float4 c0 = {acc[i][0], acc[i][1], acc[i][2], acc[i][3]};
        float4 c1 = {acc[i][4], acc[i][5], acc[i][6], acc[i][7]};
        *(float4*)&C[(size_t)m * N + bn + tx * 4] = c0;
        *(float4*)&C[(size_t)m * N + bn + 64 + tx * 4] = c1;
    }
}

// ---------------------------------------------------------------------------
// fp32 SGEMM variant: C[M,N] = At^T * B^T where At is [K][M] (M-contiguous).
// Same tile scheme; As staged directly from At rows (perfectly coalesced).
// ---------------------------------------------------------------------------
__global__ __launch_bounds__(256) void sgemm_at_bt(const float* __restrict__ At,
                                                   const float* __restrict__ B,
                                                   float* __restrict__ C,
                                                   int M, int N, int K) {
    __shared__ float As[BK][BM + 4];
    __shared__ float Bs[BK][BN + 4];
    const int tid = threadIdx.x;
    const int bm = blockIdx.y * BM;
    const int bn = blockIdx.x * BN;
    const int tx = tid & 15;
    const int ty = tid >> 4;
    const int lrow = tid >> 2;
    const int lcol = (tid & 3) * 4;

    float acc[8][8];
#pragma unroll
    for (int i = 0; i < 8; ++i)
#pragma unroll
        for (int j = 0; j < 8; ++j) acc[i][j] = 0.f;

    for (int kt = 0; kt < K; kt += BK) {
#pragma unroll
        for (int i = 0; i < 2; ++i) {
            const int idx = tid + i * 256;      // 0..511
            const int k = idx >> 5;             // 0..15
            const int mm = (idx & 31) * 4;      // 0..124
            float4 v = *(const float4*)&At[(size_t)(kt + k) * M + bm + mm];
            *(float4*)&As[k][mm] = v;
        }
#pragma unroll
        for (int i = 0; i < 2; ++i) {
            const int r = lrow + i * 64;
            float4 vb = *(const float4*)&B[(size_t)(bn + r) * K + kt + lcol];
            Bs[lcol + 0][r] = vb.x; Bs[lcol + 1][r] = vb.y;
            Bs[lcol + 2][r] = vb.z; Bs[lcol + 3][r] = vb.w;
        }
        __syncthreads();
#pragma unroll
        for (int k = 0; k < BK; ++k) {
            float4 a0 = *(const float4*)&As[k][ty * 4];
            float4 a1 = *(const float4*)&As[k][64 + ty * 4];
            float4 b0 = *(const float4*)&Bs[k][tx * 4];
            float4 b1 = *(const float4*)&Bs[k][64 + tx * 4];
            float av[8] = {a0.x, a0.y, a0.z, a0.w, a1.x, a1.y, a1.z, a1.w};
            float bv[8] = {b0.x, b0.y, b0.z, b0.w, b1.x, b1.y, b1.z, b1.w};
#pragma unroll
            for (int i = 0; i < 8; ++i)
#pragma unroll
                for (int j = 0; j < 8; ++j) acc[i][j] += av[i] * bv[j];
        }
        __syncthreads();
    }

#pragma unroll
    for (int i = 0; i < 8; ++i) {
        const int m = bm + ((i < 4) ? (ty * 4 + i) : (64 + ty * 4 + (i - 4)));
        float4 c0 = {acc[i][0], acc[i][1], acc[i][2], acc[i][3]};
        float4 c1 = {acc[i][4], acc[i][5], acc[i][6], acc[i][7]};
        *(float4*)&C[(size_t)m * N + bn + tx * 4] = c0;
        *(float4*)&C[(size_t)m * N + bn + 64 + tx * 4] = c1;
    }
}

// ---------------------------------------------------------------------------
// Depthwise causal conv (K=4) + bias + silu, LDS-transposed outputs:
//   u_t[c][m]  = silu(conv(x)+b)      (t-contiguous)
//   zs_t[c][m] = silu(z)              (t-contiguous)
// Tile: 32 channels x 64 timesteps per block, 256 threads.
// ---------------------------------------------------------------------------
#define CTT 64
#define CCC 32
__global__ __launch_bounds__(256) void conv_silu_t(const float* __restrict__ xz,
                                                   const float* __restrict__ Wc,
                                                   const float* __restrict__ bc,
                                                   float* __restrict__ u_t,
                                                   float* __restrict__ zs_t) {
    __shared__ float xs[CTT + 3][CCC];
    __shared__ float zsh[CTT][CCC];
    const int c0 = blockIdx.x * CCC;
    const int t0 = blockIdx.y * CTT;
    const int b = blockIdx.z;
    const int tid = threadIdx.x;
    const int lc = tid & 31;
    const int lt = tid >> 5;            // 0..7
    const float* xb = xz + (size_t)b * LL * (2 * DI);

#pragma unroll
    for (int i = 0; i < 9; ++i) {
        const int r = lt + i * 8;       // 0..71
        if (r < CTT + 3) {
            const int t = t0 - 3 + r;
            xs[r][lc] = (t >= 0) ? xb[(size_t)t * (2 * DI) + c0 + lc] : 0.f;
        }
    }
#pragma unroll
    for (int i = 0; i < 8; ++i) {
        const int r = lt + i * 8;
        zsh[r][lc] = xb[(size_t)(t0 + r) * (2 * DI) + DI + c0 + lc];
    }
    __syncthreads();

    const int c = c0 + lc;
    const float w0 = Wc[c * 4 + 0], w1 = Wc[c * 4 + 1];
    const float w2 = Wc[c * 4 + 2], w3 = Wc[c * 4 + 3];
    const float bcv = bc[c];
    const int tb = lt * 8;
    float uo[8], zo[8];
#pragma unroll
    for (int j = 0; j < 8; ++j) {
        const int r = tb + j;
        float acc = bcv + xs[r][lc] * w0 + xs[r + 1][lc] * w1
                        + xs[r + 2][lc] * w2 + xs[r + 3][lc] * w3;
        uo[j] = acc / (1.f + __expf(-acc));
        const float zv = zsh[r][lc];
        zo[j] = zv / (1.f + __expf(-zv));
    }
    const size_t m0 = (size_t)b * LL + t0 + tb;
    float* utp = u_t + (size_t)c * MROWS + m0;
    *(float4*)&utp[0] = make_float4(uo[0], uo[1], uo[2], uo[3]);
    *(float4*)&utp[4] = make_float4(uo[4], uo[5], uo[6], uo[7]);
    float* ztp = zs_t + (size_t)c * MROWS + m0;
    *(float4*)&ztp[0] = make_float4(zo[0], zo[1], zo[2], zo[3]);
    *(float4*)&ztp[4] = make_float4(zo[4], zo[5], zo[6], zo[7]);
}

// ---------------------------------------------------------------------------
// proj: Pt[n][m] = sum_c u_t[c][m] * Wx[n][c]   (n = 0..95), output TRANSPOSED
// Tile 16(m) x 96(n), BKp=64 over channels.
// ---------------------------------------------------------------------------
__global__ __launch_bounds__(256) void proj_gemm_t(const float* __restrict__ u_t,
                                                   const float* __restrict__ Wx,
                                                   float* __restrict__ Pt) {
    const int BKp = 64;
    __shared__ float Us[16][BKp + 1];   // Us[m-local][c-local]
    __shared__ float Ws[96][BKp + 1];
    const int tid = threadIdx.x;
    const int m0 = blockIdx.x * 16;
    const int tx = tid & 31;
    const int ty = tid >> 5;
    float acc[2][3] = {{0.f, 0.f, 0.f}, {0.f, 0.f, 0.f}};

    for (int kt = 0; kt < DI; kt += BKp) {
#pragma unroll
        for (int i = 0; i < 4; ++i) {
            const int idx = tid + i * 256;   // 0..1023
            const int mm = idx & 15;
            const int cc = idx >> 4;         // 0..63
            Us[mm][cc] = u_t[(size_t)(kt + cc) * MROWS + m0 + mm];
        }
#pragma unroll
        for (int i = 0; i < 6; ++i) {
            const int idx = tid + i * 256;
            const int r = idx >> 4;          // 0..95
            const int c4 = (idx & 15) << 2;
            float4 v = *(const float4*)&Wx[(size_t)r * DI + kt + c4];
            Ws[r][c4] = v.x; Ws[r][c4 + 1] = v.y; Ws[r][c4 + 2] = v.z; Ws[r][c4 + 3] = v.w;
        }
        __syncthreads();
#pragma unroll 8
        for (int k = 0; k < BKp; ++k) {
            const float um0 = Us[ty * 2][k];
            const float um1 = Us[ty * 2 + 1][k];
#pragma unroll
            for (int j = 0; j < 3; ++j) {
                const float w = Ws[tx + 32 * j][k];
                acc[0][j] += um0 * w;
                acc[1][j] += um1 * w;
            }
        }
        __syncthreads();
    }
#pragma unroll
    for (int i = 0; i < 2; ++i)
#pragma unroll
        for (int j = 0; j < 3; ++j)
            Pt[(size_t)(tx + 32 * j) * MROWS + m0 + ty * 2 + i] = acc[i][j];
}

// ---------------------------------------------------------------------------
// dt_t[c][m] = softplus(sum_r Pt[r][m] * Wdt[c][r] + b_dt[c]), output transposed
// Block: 256 channels x 16 m-rows.
// ---------------------------------------------------------------------------
__global__ __launch_bounds__(256) void dt_gemm_t(const float* __restrict__ Pt,
                                                 const float* __restrict__ Wdt,
                                                 const float* __restrict__ bdt,
                                                 float* __restrict__ dtb_t) {
    __shared__ float ps[64][16];
    const int tid = threadIdx.x;
    const int c = blockIdx.x * 256 + tid;
    const int m0 = blockIdx.y * 16;
#pragma unroll
    for (int i = 0; i < 4; ++i) {
        const int idx = tid + 256 * i;   // 0..1023
        const int r = idx >> 4;
        const int mm = idx & 15;
        ps[r][mm] = Pt[(size_t)r * MROWS + m0 + mm];
    }
    float w[64];
#pragma unroll
    for (int r4 = 0; r4 < 64; r4 += 4) {
        float4 v = *(const float4*)&Wdt[(size_t)c * 64 + r4];
        w[r4] = v.x; w[r4 + 1] = v.y; w[r4 + 2] = v.z; w[r4 + 3] = v.w;
    }
    const float bd = bdt[c];
    __syncthreads();
    float acc[16];
#pragma unroll
    for (int m = 0; m < 16; ++m) acc[m] = bd;
    for (int r = 0; r < 64; ++r) {
        const float wr = w[r];
        const float4 p0 = *(const float4*)&ps[r][0];
        const float4 p1 = *(const float4*)&ps[r][4];
        const float4 p2 = *(const float4*)&ps[r][8];
        const float4 p3 = *(const float4*)&ps[r][12];
        acc[0] += p0.x * wr;  acc[1] += p0.y * wr;  acc[2] += p0.z * wr;  acc[3] += p0.w * wr;
        acc[4] += p1.x * wr;  acc[5] += p1.y * wr;  acc[6] += p1.z * wr;  acc[7] += p1.w * wr;
        acc[8] += p2.x * wr;  acc[9] += p2.y * wr;  acc[10] += p2.z * wr; acc[11] += p2.w * wr;
        acc[12] += p3.x * wr; acc[13] += p3.y * wr; acc[14] += p3.z * wr; acc[15] += p3.w * wr;
    }
    float o[16];
#pragma unroll
    for (int m = 0; m < 16; ++m) {
        const float a = acc[m];
        o[m] = (a > 20.f) ? a : __logf(1.f + __expf(a));
    }
    float* dp = dtb_t + (size_t)c * MROWS + m0;
    *(float4*)&dp[0]  = make_float4(o[0], o[1], o[2], o[3]);
    *(float4*)&dp[4]  = make_float4(o[4], o[5], o[6], o[7]);
    *(float4*)&dp[8]  = make_float4(o[8], o[9], o[10], o[11]);
    *(float4*)&dp[12] = make_float4(o[12], o[13], o[14], o[15]);
}

// ---------------------------------------------------------------------------
// Selective scan + gating, all streams t-contiguous, 8-step groups with
// register double-buffered prefetch.  Lane = (b, c, s); 16-lane shfl reduce.
// Writes gated_t[c][m] (t-contiguous) for the A^T final GEMM.
// ---------------------------------------------------------------------------
__global__ __launch_bounds__(256) void scan_gate_t(const float* __restrict__ dtb_t,
                                                   const float* __restrict__ u_t,
                                                   const float* __restrict__ Pt,
                                                   const float* __restrict__ zs_t,
                                                   const float* __restrict__ A_log,
                                                   float* __restrict__ gated_t) {
    const int g = blockIdx.x * 256 + threadIdx.x;
    const int s = g & 15;
    const int cg = g >> 4;              // b*DI + c
    const int c = cg & (DI - 1);
    const int b = cg >> 11;
    const float Aval = -expf(A_log[c * 16 + s]);

    const size_t mb = (size_t)b * LL;
    const float* dtp = dtb_t + (size_t)c * MROWS + mb;
    const float* up  = u_t   + (size_t)c * MROWS + mb;
    const float* zp  = zs_t  + (size_t)c * MROWS + mb;
    const float* Bp  = Pt + (size_t)(64 + s) * MROWS + mb;
    const float* Cp  = Pt + (size_t)(80 + s) * MROWS + mb;
    float* gp = gated_t + (size_t)c * MROWS + mb;

    float4 d0 = *(const float4*)(dtp);     float4 d1 = *(const float4*)(dtp + 4);
    float4 uu0 = *(const float4*)(up);     float4 uu1 = *(const float4*)(up + 4);
    float4 B0 = *(const float4*)(Bp);      float4 B1 = *(const float4*)(Bp + 4);
    float4 C0 = *(const float4*)(Cp);      float4 C1 = *(const float4*)(Cp + 4);
    float4 z0 = *(const float4*)(zp);      float4 z1 = *(const float4*)(zp + 4);

    float h = 0.f;

#define SSTEP(dtv, uv, Bv, Cv, yy) {                 \
        const float ab = __expf((dtv) * Aval);       \
        h = ab * h + ((dtv) * (Bv)) * (uv);          \
        float y_ = (Cv) * h;                         \
        y_ += __shfl_xor(y_, 1);                     \
        y_ += __shfl_xor(y_, 2);                     \
        y_ += __shfl_xor(y_, 4);                     \
        y_ += __shfl_xor(y_, 8);                     \
        yy = y_; }

    for (int t0 = 0; t0 < LL; t0 += 8) {
        const int nt = (t0 + 8 < LL) ? (t0 + 8) : 0;   // safe dummy addr on last group
        float4 nd0 = *(const float4*)(dtp + nt);  float4 nd1 = *(const float4*)(dtp + nt + 4);
        float4 nu0 = *(const float4*)(up + nt);   float4 nu1 = *(const float4*)(up + nt + 4);
        float4 nB0 = *(const float4*)(Bp + nt);   float4 nB1 = *(const float4*)(Bp + nt + 4);
        float4 nC0 = *(const float4*)(Cp + nt);   float4 nC1 = *(const float4*)(Cp + nt + 4);
        float4 nz0 = *(const float4*)(zp + nt);   float4 nz1 = *(const float4*)(zp + nt + 4);

        float y0, y1, y2, y3, y4, y5, y6, y7;
        SSTEP(d0.x, uu0.x, B0.x, C0.x, y0);
        SSTEP(d0.y, uu0.y, B0.y, C0.y, y1);
        SSTEP(d0.z, uu0.z, B0.z, C0.z, y2);
        SSTEP(d0.w, uu0.w, B0.w, C0.w, y3);
        SSTEP(d1.x, uu1.x, B1.x, C1.x, y4);
        SSTEP(d1.y, uu1.y, B1.y, C1.y, y5);
        SSTEP(d1.z, uu1.z, B1.z, C1.z, y6);
        SSTEP(d1.w, uu1.w, B1.w, C1.w, y7);

        if (s == 0) {
            *(float4*)(gp + t0)     = make_float4(y0 * z0.x, y1 * z0.y, y2 * z0.z, y3 * z0.w);
            *(float4*)(gp + t0 + 4) = make_float4(y4 * z1.x, y5 * z1.y, y6 * z1.z, y7 * z1.w);
        }
        d0 = nd0; d1 = nd1; uu0 = nu0; uu1 = nu1;
        B0 = nB0; B1 = nB1; C0 = nC0; C1 = nC1;
        z0 = nz0; z1 = nz1;
    }
#undef SSTEP
}

// ---------------------------------------------------------------------------
extern "C" void kernel_launch(void* const* d_in, const int* in_sizes, int n_in,
                              void* d_out, int out_size, void* d_ws, size_t ws_size,
                              hipStream_t stream) {
    const float* inputs = (const float*)d_in[0];
    const float* W_in   = (const float*)d_in[1];
    const float* W_conv = (const float*)d_in[2];
    const float* b_conv = (const float*)d_in[3];
    const float* W_x    = (const float*)d_in[4];
    const float* W_dt   = (const float*)d_in[5];
    const float* b_dt   = (const float*)d_in[6];
    const float* A_log  = (const float*)d_in[7];
    const float* W_out  = (const float*)d_in[8];
    float* out = (float*)d_out;

    float* ws = (float*)d_ws;
    float* xz      = ws;                           // 2048*4096 = 8388608 floats
    float* u_t     = xz + (size_t)MROWS * 2 * DI;  // [DI][MROWS] 4194304
    float* zs_t    = u_t + (size_t)DI * MROWS;     // [DI][MROWS] 4194304
    float* Pt      = zs_t + (size_t)DI * MROWS;    // [96][MROWS] 196608
    float* dtb_t   = Pt + (size_t)96 * MROWS;      // [DI][MROWS] 4194304
    float* gated_t = xz;                           // reuse: xz dead after conv

    // 1) xz = inputs @ W_in^T      (M=2048, N=4096, K=1024)
    sgemm_bt<<<dim3(2 * DI / BN, MROWS / BM), 256, 0, stream>>>(inputs, W_in, xz, MROWS, 2 * DI, DD);
    // 2) u_t = silu(conv(x)+b)^T, zs_t = silu(z)^T
    conv_silu_t<<<dim3(DI / CCC, LL / CTT, BB), 256, 0, stream>>>(xz, W_conv, b_conv, u_t, zs_t);
    // 3) Pt = (u @ W_x^T)^T        ([96][MROWS])
    proj_gemm_t<<<dim3(MROWS / 16), 256, 0, stream>>>(u_t, W_x, Pt);
    // 4) dtb_t = softplus(dt_raw @ W_dt^T + b_dt)^T
    dt_gemm_t<<<dim3(DI / 256, MROWS / 16), 256, 0, stream>>>(Pt, W_dt, b_dt, dtb_t);
    // 5) scan + gate -> gated_t [DI][MROWS]
    scan_gate_t<<<dim3(BB * DI * SS / 256), 256, 0, stream>>>(dtb_t, u_t, Pt, zs_t, A_log, gated_t);
    // 6) out = gated @ W_out^T     (A^T variant: gated_t is [K][M])
    sgemm_at_bt<<<dim3(DD / BN, MROWS / BM), 256, 0, stream>>>(gated_t, W_out, out, MROWS, DD, DI);
}

// Round 3
// 639.095 us; speedup vs baseline: 1.5810x; 1.1455x over previous
//
#include <hip/hip_runtime.h>
#include <hip/hip_bf16.h>

// Problem constants
#define BB 2
#define LL 1024
#define DD 1024
#define DI 2048
#define SS 16
#define KK 4
#define RR 64
#define MROWS (BB*LL)   // 2048

// ---------------------------------------------------------------------------
// fp32 SGEMM w/ split-K: Cpart[z][M,N] = A[M,Kz] * B[N,Kz]^T  (A row-major)
// 128x128 tile, BK=16, 256 threads, 8x8 micro-tile. blockIdx.z = K-split.
// ---------------------------------------------------------------------------
#define BM 128
#define BN 128
#define BK 16

__global__ __launch_bounds__(256) void sgemm_bt_sk(const float* __restrict__ A,
                                                   const float* __restrict__ B,
                                                   float* __restrict__ C,
                                                   int M, int N, int K, int Klen) {
    __shared__ float As[BK][BM + 4];
    __shared__ float Bs[BK][BN + 4];
    const int tid = threadIdx.x;
    const int bm = blockIdx.y * BM;
    const int bn = blockIdx.x * BN;
    const int Koff = blockIdx.z * Klen;
    float* __restrict__ Cp = C + (size_t)blockIdx.z * M * N;
    const int tx = tid & 15;
    const int ty = tid >> 4;
    const int lrow = tid >> 2;
    const int lcol = (tid & 3) * 4;

    float acc[8][8];
#pragma unroll
    for (int i = 0; i < 8; ++i)
#pragma unroll
        for (int j = 0; j < 8; ++j) acc[i][j] = 0.f;

    for (int kt = Koff; kt < Koff + Klen; kt += BK) {
#pragma unroll
        for (int i = 0; i < 2; ++i) {
            const int r = lrow + i * 64;
            float4 va = *(const float4*)&A[(size_t)(bm + r) * K + kt + lcol];
            As[lcol + 0][r] = va.x; As[lcol + 1][r] = va.y;
            As[lcol + 2][r] = va.z; As[lcol + 3][r] = va.w;
            float4 vb = *(const float4*)&B[(size_t)(bn + r) * K + kt + lcol];
            Bs[lcol + 0][r] = vb.x; Bs[lcol + 1][r] = vb.y;
            Bs[lcol + 2][r] = vb.z; Bs[lcol + 3][r] = vb.w;
        }
        __syncthreads();
#pragma unroll
        for (int k = 0; k < BK; ++k) {
            float4 a0 = *(const float4*)&As[k][ty * 4];
            float4 a1 = *(const float4*)&As[k][64 + ty * 4];
            float4 b0 = *(const float4*)&Bs[k][tx * 4];
            float4 b1 = *(const float4*)&Bs[k][64 + tx * 4];
            float av[8] = {a0.x, a0.y, a0.z, a0.w, a1.x, a1.y, a1.z, a1.w};
            float bv[8] = {b0.x, b0.y, b0.z, b0.w, b1.x, b1.y, b1.z, b1.w};
#pragma unroll
            for (int i = 0; i < 8; ++i)
#pragma unroll
                for (int j = 0; j < 8; ++j) acc[i][j] += av[i] * bv[j];
        }
        __syncthreads();
    }

#pragma unroll
    for (int i = 0; i < 8; ++i) {
        const int m = bm + ((i < 4) ? (ty * 4 + i) : (64 + ty * 4 + (i - 4)));
        float4 c0 = {acc[i][0], acc[i][1], acc[i][2], acc[i][3]};
        float4 c1 = {acc[i][4], acc[i][5], acc[i][6], acc[i][7]};
        *(float4*)&Cp[(size_t)m * N + bn + tx * 4] = c0;
        *(float4*)&Cp[(size_t)m * N + bn + 64 + tx * 4] = c1;
    }
}

// ---------------------------------------------------------------------------
// Split-K variant with A pre-transposed: At is [K][M] (M-contiguous).
// ---------------------------------------------------------------------------
__global__ __launch_bounds__(256) void sgemm_at_bt_sk(const float* __restrict__ At,
                                                      const float* __restrict__ B,
                                                      float* __restrict__ C,
                                                      int M, int N, int K, int Klen) {
    __shared__ float As[BK][BM + 4];
    __shared__ float Bs[BK][BN + 4];
    const int tid = threadIdx.x;
    const int bm = blockIdx.y * BM;
    const int bn = blockIdx.x * BN;
    const int Koff = blockIdx.z * Klen;
    float* __restrict__ Cp = C + (size_t)blockIdx.z * M * N;
    const int tx = tid & 15;
    const int ty = tid >> 4;
    const int lrow = tid >> 2;
    const int lcol = (tid & 3) * 4;

    float acc[8][8];
#pragma unroll
    for (int i = 0; i < 8; ++i)
#pragma unroll
        for (int j = 0; j < 8; ++j) acc[i][j] = 0.f;

    for (int kt = Koff; kt < Koff + Klen; kt += BK) {
#pragma unroll
        for (int i = 0; i < 2; ++i) {
            const int idx = tid + i * 256;      // 0..511
            const int k = idx >> 5;             // 0..15
            const int mm = (idx & 31) * 4;      // 0..124
            float4 v = *(const float4*)&At[(size_t)(kt + k) * M + bm + mm];
            *(float4*)&As[k][mm] = v;
        }
#pragma unroll
        for (int i = 0; i < 2; ++i) {
            const int r = lrow + i * 64;
            float4 vb = *(const float4*)&B[(size_t)(bn + r) * K + kt + lcol];
            Bs[lcol + 0][r] = vb.x; Bs[lcol + 1][r] = vb.y;
            Bs[lcol + 2][r] = vb.z; Bs[lcol + 3][r] = vb.w;
        }
        __syncthreads();
#pragma unroll
        for (int k = 0; k < BK; ++k) {
            float4 a0 = *(const float4*)&As[k][ty * 4];
            float4 a1 = *(const float4*)&As[k][64 + ty * 4];
            float4 b0 = *(const float4*)&Bs[k][tx * 4];
            float4 b1 = *(const float4*)&Bs[k][64 + tx * 4];
            float av[8] = {a0.x, a0.y, a0.z, a0.w, a1.x, a1.y, a1.z, a1.w};
            float bv[8] = {b0.x, b0.y, b0.z, b0.w, b1.x, b1.y, b1.z, b1.w};
#pragma unroll
            for (int i = 0; i < 8; ++i)
#pragma unroll
                for (int j = 0; j < 8; ++j) acc[i][j] += av[i] * bv[j];
        }
        __syncthreads();
    }

#pragma unroll
    for (int i = 0; i < 8; ++i) {
        const int m = bm + ((i < 4) ? (ty * 4 + i) : (64 + ty * 4 + (i - 4)));
        float4 c0 = {acc[i][0], acc[i][1], acc[i][2], acc[i][3]};
        float4 c1 = {acc[i][4], acc[i][5], acc[i][6], acc[i][7]};
        *(float4*)&Cp[(size_t)m * N + bn + tx * 4] = c0;
        *(float4*)&Cp[(size_t)m * N + bn + 64 + tx * 4] = c1;
    }
}

// ---------------------------------------------------------------------------
// dst4[i] += src4[i]   (split-K=2 reduce, in place)
// ---------------------------------------------------------------------------
__global__ __launch_bounds__(256) void reduce_add_inplace(float4* __restrict__ dst,
                                                          const float4* __restrict__ src,
                                                          int n4) {
    for (int i = blockIdx.x * 256 + threadIdx.x; i < n4; i += gridDim.x * 256) {
        float4 a = dst[i];
        const float4 b = src[i];
        a.x += b.x; a.y += b.y; a.z += b.z; a.w += b.w;
        dst[i] = a;
    }
}

// ---------------------------------------------------------------------------
// dst4[i] = sum_{s<4} src4[i + s*n4]   (split-K=4 reduce)
// ---------------------------------------------------------------------------
__global__ __launch_bounds__(256) void reduce_sum4(float4* __restrict__ dst,
                                                   const float4* __restrict__ src,
                                                   int n4) {
    for (int i = blockIdx.x * 256 + threadIdx.x; i < n4; i += gridDim.x * 256) {
        const float4 a = src[i];
        const float4 b = src[i + (size_t)n4];
        const float4 c = src[i + (size_t)2 * n4];
        const float4 d = src[i + (size_t)3 * n4];
        dst[i] = make_float4(a.x + b.x + c.x + d.x, a.y + b.y + c.y + d.y,
                             a.z + b.z + c.z + d.z, a.w + b.w + c.w + d.w);
    }
}

// ---------------------------------------------------------------------------
// Depthwise causal conv (K=4) + bias + silu, LDS-transposed outputs:
//   u_t[c][m]  = silu(conv(x)+b)      (t-contiguous)
//   zs_t[c][m] = silu(z)              (t-contiguous)
// ---------------------------------------------------------------------------
#define CTT 64
#define CCC 32
__global__ __launch_bounds__(256) void conv_silu_t(const float* __restrict__ xz,
                                                   const float* __restrict__ Wc,
                                                   const float* __restrict__ bc,
                                                   float* __restrict__ u_t,
                                                   float* __restrict__ zs_t) {
    __shared__ float xs[CTT + 3][CCC];
    __shared__ float zsh[CTT][CCC];
    const int c0 = blockIdx.x * CCC;
    const int t0 = blockIdx.y * CTT;
    const int b = blockIdx.z;
    const int tid = threadIdx.x;
    const int lc = tid & 31;
    const int lt = tid >> 5;            // 0..7
    const float* xb = xz + (size_t)b * LL * (2 * DI);

#pragma unroll
    for (int i = 0; i < 9; ++i) {
        const int r = lt + i * 8;       // 0..71
        if (r < CTT + 3) {
            const int t = t0 - 3 + r;
            xs[r][lc] = (t >= 0) ? xb[(size_t)t * (2 * DI) + c0 + lc] : 0.f;
        }
    }
#pragma unroll
    for (int i = 0; i < 8; ++i) {
        const int r = lt + i * 8;
        zsh[r][lc] = xb[(size_t)(t0 + r) * (2 * DI) + DI + c0 + lc];
    }
    __syncthreads();

    const int c = c0 + lc;
    const float w0 = Wc[c * 4 + 0], w1 = Wc[c * 4 + 1];
    const float w2 = Wc[c * 4 + 2], w3 = Wc[c * 4 + 3];
    const float bcv = bc[c];
    const int tb = lt * 8;
    float uo[8], zo[8];
#pragma unroll
    for (int j = 0; j < 8; ++j) {
        const int r = tb + j;
        float acc = bcv + xs[r][lc] * w0 + xs[r + 1][lc] * w1
                        + xs[r + 2][lc] * w2 + xs[r + 3][lc] * w3;
        uo[j] = acc / (1.f + __expf(-acc));
        const float zv = zsh[r][lc];
        zo[j] = zv / (1.f + __expf(-zv));
    }
    const size_t m0 = (size_t)b * LL + t0 + tb;
    float* utp = u_t + (size_t)c * MROWS + m0;
    *(float4*)&utp[0] = make_float4(uo[0], uo[1], uo[2], uo[3]);
    *(float4*)&utp[4] = make_float4(uo[4], uo[5], uo[6], uo[7]);
    float* ztp = zs_t + (size_t)c * MROWS + m0;
    *(float4*)&ztp[0] = make_float4(zo[0], zo[1], zo[2], zo[3]);
    *(float4*)&ztp[4] = make_float4(zo[4], zo[5], zo[6], zo[7]);
}

// ---------------------------------------------------------------------------
// proj: Pt[n][m] = sum_c u_t[c][m] * Wx[n][c]   (n = 0..95), output TRANSPOSED
// ---------------------------------------------------------------------------
__global__ __launch_bounds__(256) void proj_gemm_t(const float* __restrict__ u_t,
                                                   const float* __restrict__ Wx,
                                                   float* __restrict__ Pt) {
    const int BKp = 64;
    __shared__ float Us[16][BKp + 1];
    __shared__ float Ws[96][BKp + 1];
    const int tid = threadIdx.x;
    const int m0 = blockIdx.x * 16;
    const int tx = tid & 31;
    const int ty = tid >> 5;
    float acc[2][3] = {{0.f, 0.f, 0.f}, {0.f, 0.f, 0.f}};

    for (int kt = 0; kt < DI; kt += BKp) {
#pragma unroll
        for (int i = 0; i < 4; ++i) {
            const int idx = tid + i * 256;   // 0..1023
            const int mm = idx & 15;
            const int cc = idx >> 4;         // 0..63
            Us[mm][cc] = u_t[(size_t)(kt + cc) * MROWS + m0 + mm];
        }
#pragma unroll
        for (int i = 0; i < 6; ++i) {
            const int idx = tid + i * 256;
            const int r = idx >> 4;          // 0..95
            const int c4 = (idx & 15) << 2;
            float4 v = *(const float4*)&Wx[(size_t)r * DI + kt + c4];
            Ws[r][c4] = v.x; Ws[r][c4 + 1] = v.y; Ws[r][c4 + 2] = v.z; Ws[r][c4 + 3] = v.w;
        }
        __syncthreads();
#pragma unroll 8
        for (int k = 0; k < BKp; ++k) {
            const float um0 = Us[ty * 2][k];
            const float um1 = Us[ty * 2 + 1][k];
#pragma unroll
            for (int j = 0; j < 3; ++j) {
                const float w = Ws[tx + 32 * j][k];
                acc[0][j] += um0 * w;
                acc[1][j] += um1 * w;
            }
        }
        __syncthreads();
    }
#pragma unroll
    for (int i = 0; i < 2; ++i)
#pragma unroll
        for (int j = 0; j < 3; ++j)
            Pt[(size_t)(tx + 32 * j) * MROWS + m0 + ty * 2 + i] = acc[i][j];
}

// ---------------------------------------------------------------------------
// dt_t[c][m] = softplus(sum_r Pt[r][m] * Wdt[c][r] + b_dt[c]), transposed out
// ---------------------------------------------------------------------------
__global__ __launch_bounds__(256) void dt_gemm_t(const float* __restrict__ Pt,
                                                 const float* __restrict__ Wdt,
                                                 const float* __restrict__ bdt,
                                                 float* __restrict__ dtb_t) {
    __shared__ float ps[64][16];
    const int tid = threadIdx.x;
    const int c = blockIdx.x * 256 + tid;
    const int m0 = blockIdx.y * 16;
#pragma unroll
    for (int i = 0; i < 4; ++i) {
        const int idx = tid + 256 * i;   // 0..1023
        const int r = idx >> 4;
        const int mm = idx & 15;
        ps[r][mm] = Pt[(size_t)r * MROWS + m0 + mm];
    }
    float w[64];
#pragma unroll
    for (int r4 = 0; r4 < 64; r4 += 4) {
        float4 v = *(const float4*)&Wdt[(size_t)c * 64 + r4];
        w[r4] = v.x; w[r4 + 1] = v.y; w[r4 + 2] = v.z; w[r4 + 3] = v.w;
    }
    const float bd = bdt[c];
    __syncthreads();
    float acc[16];
#pragma unroll
    for (int m = 0; m < 16; ++m) acc[m] = bd;
    for (int r = 0; r < 64; ++r) {
        const float wr = w[r];
        const float4 p0 = *(const float4*)&ps[r][0];
        const float4 p1 = *(const float4*)&ps[r][4];
        const float4 p2 = *(const float4*)&ps[r][8];
        const float4 p3 = *(const float4*)&ps[r][12];
        acc[0] += p0.x * wr;  acc[1] += p0.y * wr;  acc[2] += p0.z * wr;  acc[3] += p0.w * wr;
        acc[4] += p1.x * wr;  acc[5] += p1.y * wr;  acc[6] += p1.z * wr;  acc[7] += p1.w * wr;
        acc[8] += p2.x * wr;  acc[9] += p2.y * wr;  acc[10] += p2.z * wr; acc[11] += p2.w * wr;
        acc[12] += p3.x * wr; acc[13] += p3.y * wr; acc[14] += p3.z * wr; acc[15] += p3.w * wr;
    }
    float o[16];
#pragma unroll
    for (int m = 0; m < 16; ++m) {
        const float a = acc[m];
        o[m] = (a > 20.f) ? a : __logf(1.f + __expf(a));
    }
    float* dp = dtb_t + (size_t)c * MROWS + m0;
    *(float4*)&dp[0]  = make_float4(o[0], o[1], o[2], o[3]);
    *(float4*)&dp[4]  = make_float4(o[4], o[5], o[6], o[7]);
    *(float4*)&dp[8]  = make_float4(o[8], o[9], o[10], o[11]);
    *(float4*)&dp[12] = make_float4(o[12], o[13], o[14], o[15]);
}

// ---------------------------------------------------------------------------
// Selective scan + gating, all streams t-contiguous, 8-step groups with
// register double-buffered prefetch.  Writes gated_t[c][m].
// ---------------------------------------------------------------------------
__global__ __launch_bounds__(256) void scan_gate_t(const float* __restrict__ dtb_t,
                                                   const float* __restrict__ u_t,
                                                   const float* __restrict__ Pt,
                                                   const float* __restrict__ zs_t,
                                                   const float* __restrict__ A_log,
                                                   float* __restrict__ gated_t) {
    const int g = blockIdx.x * 256 + threadIdx.x;
    const int s = g & 15;
    const int cg = g >> 4;              // b*DI + c
    const int c = cg & (DI - 1);
    const int b = cg >> 11;
    const float Aval = -expf(A_log[c * 16 + s]);

    const size_t mb = (size_t)b * LL;
    const float* dtp = dtb_t + (size_t)c * MROWS + mb;
    const float* up  = u_t   + (size_t)c * MROWS + mb;
    const float* zp  = zs_t  + (size_t)c * MROWS + mb;
    const float* Bp  = Pt + (size_t)(64 + s) * MROWS + mb;
    const float* Cp  = Pt + (size_t)(80 + s) * MROWS + mb;
    float* gp = gated_t + (size_t)c * MROWS + mb;

    float4 d0 = *(const float4*)(dtp);     float4 d1 = *(const float4*)(dtp + 4);
    float4 uu0 = *(const float4*)(up);     float4 uu1 = *(const float4*)(up + 4);
    float4 B0 = *(const float4*)(Bp);      float4 B1 = *(const float4*)(Bp + 4);
    float4 C0 = *(const float4*)(Cp);      float4 C1 = *(const float4*)(Cp + 4);
    float4 z0 = *(const float4*)(zp);      float4 z1 = *(const float4*)(zp + 4);

    float h = 0.f;

#define SSTEP(dtv, uv, Bv, Cv, yy) {                 \
        const float ab = __expf((dtv) * Aval);       \
        h = ab * h + ((dtv) * (Bv)) * (uv);          \
        float y_ = (Cv) * h;                         \
        y_ += __shfl_xor(y_, 1);                     \
        y_ += __shfl_xor(y_, 2);                     \
        y_ += __shfl_xor(y_, 4);                     \
        y_ += __shfl_xor(y_, 8);                     \
        yy = y_; }

    for (int t0 = 0; t0 < LL; t0 += 8) {
        const int nt = (t0 + 8 < LL) ? (t0 + 8) : 0;
        float4 nd0 = *(const float4*)(dtp + nt);  float4 nd1 = *(const float4*)(dtp + nt + 4);
        float4 nu0 = *(const float4*)(up + nt);   float4 nu1 = *(const float4*)(up + nt + 4);
        float4 nB0 = *(const float4*)(Bp + nt);   float4 nB1 = *(const float4*)(Bp + nt + 4);
        float4 nC0 = *(const float4*)(Cp + nt);   float4 nC1 = *(const float4*)(Cp + nt + 4);
        float4 nz0 = *(const float4*)(zp + nt);   float4 nz1 = *(const float4*)(zp + nt + 4);

        float y0, y1, y2, y3, y4, y5, y6, y7;
        SSTEP(d0.x, uu0.x, B0.x, C0.x, y0);
        SSTEP(d0.y, uu0.y, B0.y, C0.y, y1);
        SSTEP(d0.z, uu0.z, B0.z, C0.z, y2);
        SSTEP(d0.w, uu0.w, B0.w, C0.w, y3);
        SSTEP(d1.x, uu1.x, B1.x, C1.x, y4);
        SSTEP(d1.y, uu1.y, B1.y, C1.y, y5);
        SSTEP(d1.z, uu1.z, B1.z, C1.z, y6);
        SSTEP(d1.w, uu1.w, B1.w, C1.w, y7);

        if (s == 0) {
            *(float4*)(gp + t0)     = make_float4(y0 * z0.x, y1 * z0.y, y2 * z0.z, y3 * z0.w);
            *(float4*)(gp + t0 + 4) = make_float4(y4 * z1.x, y5 * z1.y, y6 * z1.z, y7 * z1.w);
        }
        d0 = nd0; d1 = nd1; uu0 = nu0; uu1 = nu1;
        B0 = nB0; B1 = nB1; C0 = nC0; C1 = nC1;
        z0 = nz0; z1 = nz1;
    }
#undef SSTEP
}

// ---------------------------------------------------------------------------
// Workspace layout (floats), total 21,168,128 (= round-2 proven footprint):
//   [0        , 8388608 )  xz        (also GEMM1 partial-0; later gated_t in [0,4194304))
//   [8388608  , 16777216)  GEMM1 partial-1 (dead after reduce1);
//                          then u_t [8388608,12582912), zs_t [12582912,16777216)
//                          then GEMM2 partials P2 (4 x 2097152) after scan
//   [16777216 , 16973824)  Pt
//   [16973824 , 21168128)  dtb_t
// ---------------------------------------------------------------------------
extern "C" void kernel_launch(void* const* d_in, const int* in_sizes, int n_in,
                              void* d_out, int out_size, void* d_ws, size_t ws_size,
                              hipStream_t stream) {
    const float* inputs = (const float*)d_in[0];
    const float* W_in   = (const float*)d_in[1];
    const float* W_conv = (const float*)d_in[2];
    const float* b_conv = (const float*)d_in[3];
    const float* W_x    = (const float*)d_in[4];
    const float* W_dt   = (const float*)d_in[5];
    const float* b_dt   = (const float*)d_in[6];
    const float* A_log  = (const float*)d_in[7];
    const float* W_out  = (const float*)d_in[8];
    float* out = (float*)d_out;

    float* ws = (float*)d_ws;
    float* xz      = ws;                      // 8388608
    float* p1b     = ws + 8388608;            // GEMM1 partial 1 (== xz + M*N)
    float* u_t     = ws + 8388608;            // after reduce1
    float* zs_t    = ws + 12582912;
    float* P2      = ws + 8388608;            // after scan (4 x 2097152)
    float* Pt      = ws + 16777216;
    float* dtb_t   = ws + 16973824;
    float* gated_t = ws;                      // xz dead after conv

    // 1) xz = inputs @ W_in^T  (M=2048,N=4096,K=1024), split-K=2 -> 1024 blocks
    sgemm_bt_sk<<<dim3(2 * DI / BN, MROWS / BM, 2), 256, 0, stream>>>(
        inputs, W_in, xz, MROWS, 2 * DI, DD, DD / 2);
    // 1b) xz += partial1
    reduce_add_inplace<<<4096, 256, 0, stream>>>((float4*)xz, (const float4*)p1b,
                                                 8388608 / 4);
    // 2) u_t = silu(conv(x)+b)^T, zs_t = silu(z)^T   (overwrites dead p1b)
    conv_silu_t<<<dim3(DI / CCC, LL / CTT, BB), 256, 0, stream>>>(xz, W_conv, b_conv, u_t, zs_t);
    // 3) Pt = (u @ W_x^T)^T
    proj_gemm_t<<<dim3(MROWS / 16), 256, 0, stream>>>(u_t, W_x, Pt);
    // 4) dtb_t = softplus(dt_raw @ W_dt^T + b_dt)^T
    dt_gemm_t<<<dim3(DI / 256, MROWS / 16), 256, 0, stream>>>(Pt, W_dt, b_dt, dtb_t);
    // 5) scan + gate -> gated_t (in dead xz region)
    scan_gate_t<<<dim3(BB * DI * SS / 256), 256, 0, stream>>>(dtb_t, u_t, Pt, zs_t, A_log, gated_t);
    // 6) P2[z] = gated^T-slice @ W_out^T  (M=2048,N=1024,K=2048), split-K=4 -> 512 blocks
    //    (P2 overlays dead u_t/zs_t; gated_t at ws[0..4194304) not touched)
    sgemm_at_bt_sk<<<dim3(DD / BN, MROWS / BM, 4), 256, 0, stream>>>(
        gated_t, W_out, P2, MROWS, DD, DI, DI / 4);
    // 6b) out = sum of 4 partials
    reduce_sum4<<<2048, 256, 0, stream>>>((float4*)out, (const float4*)P2, 2097152 / 4);
}

// Round 4
// 490.158 us; speedup vs baseline: 2.0613x; 1.3039x over previous
//
#include <hip/hip_runtime.h>
#include <hip/hip_bf16.h>

// Problem constants
#define BB 2
#define LL 1024
#define DD 1024
#define DI 2048
#define SS 16
#define KK 4
#define RR 64
#define MROWS (BB*LL)   // 2048

typedef __attribute__((ext_vector_type(8))) short short8;     // 8 bf16 = 4 VGPR
typedef __attribute__((ext_vector_type(4))) float floatx4;    // MFMA C/D

// RNE fp32 -> bf16 bits
__device__ __forceinline__ unsigned short f2bf(float v) {
    unsigned int u = __float_as_uint(v);
    return (unsigned short)((u + 0x7FFFu + ((u >> 16) & 1u)) >> 16);
}
__device__ __forceinline__ float bf2f(unsigned short h) {
    return __uint_as_float(((unsigned int)h) << 16);
}
__device__ __forceinline__ void split1(float v, unsigned short& a,
                                       unsigned short& b, unsigned short& c) {
    a = f2bf(v);
    float r = v - bf2f(a);
    b = f2bf(r);
    float r2 = r - bf2f(b);
    c = f2bf(r2);
}

// ---------------------------------------------------------------------------
// split3: fp32[n] -> three bf16[n] (hi, mid, lo), elementwise
// ---------------------------------------------------------------------------
__global__ __launch_bounds__(256) void split3(const float4* __restrict__ src,
                                              ushort4* __restrict__ d1,
                                              ushort4* __restrict__ d2,
                                              ushort4* __restrict__ d3, int n4) {
    for (int i = blockIdx.x * 256 + threadIdx.x; i < n4; i += gridDim.x * 256) {
        const float4 v = src[i];
        ushort4 o1, o2, o3;
        split1(v.x, o1.x, o2.x, o3.x);
        split1(v.y, o1.y, o2.y, o3.y);
        split1(v.z, o1.z, o2.z, o3.z);
        split1(v.w, o1.w, o2.w, o3.w);
        d1[i] = o1; d2[i] = o2; d3[i] = o3;
    }
}

// ---------------------------------------------------------------------------
// split3_t: src [2048][2048] (k-major) -> three bf16 [M][K] (transposed),
// 64x64 LDS tile.
// ---------------------------------------------------------------------------
__global__ __launch_bounds__(256) void split3_t(const float* __restrict__ src,
                                                unsigned short* __restrict__ d1,
                                                unsigned short* __restrict__ d2,
                                                unsigned short* __restrict__ d3) {
    __shared__ float xs[64][68];
    const int m0 = blockIdx.x * 64;
    const int k0 = blockIdx.y * 64;
    const int tid = threadIdx.x;
    {
        const int r = tid >> 2;            // k-local
        const int cb = (tid & 3) * 16;     // m-local base
#pragma unroll
        for (int i = 0; i < 4; ++i) {
            float4 v = *(const float4*)&src[(size_t)(k0 + r) * 2048 + m0 + cb + i * 4];
            *(float4*)&xs[r][cb + i * 4] = v;
        }
    }
    __syncthreads();
    const int mm = tid >> 2;               // m-local
    const int kb = (tid & 3) * 16;         // k-local base
    const size_t obase = (size_t)(m0 + mm) * 2048 + k0 + kb;
#pragma unroll
    for (int g = 0; g < 4; ++g) {
        ushort4 o1, o2, o3;
        split1(xs[kb + g * 4 + 0][mm], o1.x, o2.x, o3.x);
        split1(xs[kb + g * 4 + 1][mm], o1.y, o2.y, o3.y);
        split1(xs[kb + g * 4 + 2][mm], o1.z, o2.z, o3.z);
        split1(xs[kb + g * 4 + 3][mm], o1.w, o2.w, o3.w);
        *(ushort4*)&d1[obase + g * 4] = o1;
        *(ushort4*)&d2[obase + g * 4] = o2;
        *(ushort4*)&d3[obase + g * 4] = o3;
    }
}

// ---------------------------------------------------------------------------
// Split-bf16 MFMA GEMM: C[M,N] = A[M,K]*B[N,K]^T in fp32-equivalent precision
// via 3-way bf16 splits and 6 MFMA products per k-chunk.
// 128x128 tile, BK=32, 256 threads = 4 waves, each wave 4x4 of 16x16x32.
// blockIdx.z selects K-window and output buffer (C0 / C1 partial).
// ---------------------------------------------------------------------------
__global__ __launch_bounds__(256, 2) void gemm_mfma_split(
    const unsigned short* __restrict__ A1, const unsigned short* __restrict__ A2,
    const unsigned short* __restrict__ A3,
    const unsigned short* __restrict__ B1, const unsigned short* __restrict__ B2,
    const unsigned short* __restrict__ B3,
    float* __restrict__ C0, float* __restrict__ C1,
    int M, int N, int Kstride, int Klen) {
    __shared__ unsigned short As[3][128][40];   // [split][m][k], pad 32->40
    __shared__ unsigned short Bs[3][128][40];   // [split][n][k]
    const int tid = threadIdx.x;
    const int bm = blockIdx.y * 128;
    const int bn = blockIdx.x * 128;
    const int Koff = blockIdx.z * Klen;
    float* __restrict__ C = blockIdx.z ? C1 : C0;

    const int lane = tid & 63;
    const int wv = tid >> 6;
    const int lm = lane & 15;
    const int kq = lane >> 4;             // 0..3 (k-quad on input, row-quad on output)
    const int wm = (wv >> 1) * 64;
    const int wn = (wv & 1) * 64;

    floatx4 acc[4][4];
    const floatx4 zf = {0.f, 0.f, 0.f, 0.f};
#pragma unroll
    for (int i = 0; i < 4; ++i)
#pragma unroll
        for (int j = 0; j < 4; ++j) acc[i][j] = zf;

    const unsigned short* Ap0 = A1; const unsigned short* Ap1 = A2; const unsigned short* Ap2 = A3;
    const unsigned short* Bp0 = B1; const unsigned short* Bp1 = B2; const unsigned short* Bp2 = B3;

    const int ch0 = tid * 2;              // chunk ids: ch0, ch0+1
    const int row0 = ch0 >> 2;            // 0..127 (pairs of chunks share row? no: 4 chunks/row)
    const int kc0 = (ch0 & 3) * 8;

    for (int kt = Koff; kt < Koff + Klen; kt += 32) {
        // ---- stage 3 splits of A and B (each thread: 2 chunks of 8 bf16/side/split)
#define STAGE(p, SRC_A, SRC_B)                                                          \
        {                                                                               \
            const int r0 = (ch0) >> 2, c0 = ((ch0) & 3) * 8;                            \
            const int r1 = (ch0 + 1) >> 2, c1 = ((ch0 + 1) & 3) * 8;                    \
            *(short8*)&As[p][r0][c0] = *(const short8*)&SRC_A[(size_t)(bm + r0) * Kstride + kt + c0]; \
            *(short8*)&As[p][r1][c1] = *(const short8*)&SRC_A[(size_t)(bm + r1) * Kstride + kt + c1]; \
            *(short8*)&Bs[p][r0][c0] = *(const short8*)&SRC_B[(size_t)(bn + r0) * Kstride + kt + c0]; \
            *(short8*)&Bs[p][r1][c1] = *(const short8*)&SRC_B[(size_t)(bn + r1) * Kstride + kt + c1]; \
        }
        STAGE(0, Ap0, Bp0)
        STAGE(1, Ap1, Bp1)
        STAGE(2, Ap2, Bp2)
#undef STAGE
        __syncthreads();

        // ---- fragments: af for all 3 splits, bf per split on the fly
        short8 af[3][4];
#pragma unroll
        for (int p = 0; p < 3; ++p)
#pragma unroll
            for (int i = 0; i < 4; ++i)
                af[p][i] = *(const short8*)&As[p][wm + i * 16 + lm][kq * 8];

#define PROD(p, bfq)                                                                     \
        _Pragma("unroll")                                                                \
        for (int i = 0; i < 4; ++i)                                                      \
            _Pragma("unroll")                                                            \
            for (int j = 0; j < 4; ++j)                                                  \
                acc[i][j] = __builtin_amdgcn_mfma_f32_16x16x32_bf16(af[p][i], bfq[j],    \
                                                                    acc[i][j], 0, 0, 0);
        {
            short8 bfq[4];
#pragma unroll
            for (int j = 0; j < 4; ++j) bfq[j] = *(const short8*)&Bs[0][wn + j * 16 + lm][kq * 8];
            PROD(0, bfq)   // a1*b1
            PROD(1, bfq)   // a2*b1
            PROD(2, bfq)   // a3*b1
        }
        {
            short8 bfq[4];
#pragma unroll
            for (int j = 0; j < 4; ++j) bfq[j] = *(const short8*)&Bs[1][wn + j * 16 + lm][kq * 8];
            PROD(0, bfq)   // a1*b2
            PROD(1, bfq)   // a2*b2
        }
        {
            short8 bfq[4];
#pragma unroll
            for (int j = 0; j < 4; ++j) bfq[j] = *(const short8*)&Bs[2][wn + j * 16 + lm][kq * 8];
            PROD(0, bfq)   // a1*b3
        }
#undef PROD
        __syncthreads();
    }

    // ---- epilogue: D row = (lane>>4)*4 + reg, col = lane&15
#pragma unroll
    for (int i = 0; i < 4; ++i) {
        const int mrow = bm + wm + i * 16 + kq * 4;
#pragma unroll
        for (int j = 0; j < 4; ++j) {
            const int col = bn + wn + j * 16 + lm;
#pragma unroll
            for (int r = 0; r < 4; ++r)
                C[(size_t)(mrow + r) * N + col] = acc[i][j][r];
        }
    }
}

// ---------------------------------------------------------------------------
// dst4[i] += src4[i]
// ---------------------------------------------------------------------------
__global__ __launch_bounds__(256) void reduce_add_inplace(float4* __restrict__ dst,
                                                          const float4* __restrict__ src,
                                                          int n4) {
    for (int i = blockIdx.x * 256 + threadIdx.x; i < n4; i += gridDim.x * 256) {
        float4 a = dst[i];
        const float4 b = src[i];
        a.x += b.x; a.y += b.y; a.z += b.z; a.w += b.w;
        dst[i] = a;
    }
}

// ---------------------------------------------------------------------------
// Depthwise causal conv (K=4) + bias + silu, transposed outputs (unchanged)
// ---------------------------------------------------------------------------
#define CTT 64
#define CCC 32
__global__ __launch_bounds__(256) void conv_silu_t(const float* __restrict__ xz,
                                                   const float* __restrict__ Wc,
                                                   const float* __restrict__ bc,
                                                   float* __restrict__ u_t,
                                                   float* __restrict__ zs_t) {
    __shared__ float xs[CTT + 3][CCC];
    __shared__ float zsh[CTT][CCC];
    const int c0 = blockIdx.x * CCC;
    const int t0 = blockIdx.y * CTT;
    const int b = blockIdx.z;
    const int tid = threadIdx.x;
    const int lc = tid & 31;
    const int lt = tid >> 5;
    const float* xb = xz + (size_t)b * LL * (2 * DI);

#pragma unroll
    for (int i = 0; i < 9; ++i) {
        const int r = lt + i * 8;
        if (r < CTT + 3) {
            const int t = t0 - 3 + r;
            xs[r][lc] = (t >= 0) ? xb[(size_t)t * (2 * DI) + c0 + lc] : 0.f;
        }
    }
#pragma unroll
    for (int i = 0; i < 8; ++i) {
        const int r = lt + i * 8;
        zsh[r][lc] = xb[(size_t)(t0 + r) * (2 * DI) + DI + c0 + lc];
    }
    __syncthreads();

    const int c = c0 + lc;
    const float w0 = Wc[c * 4 + 0], w1 = Wc[c * 4 + 1];
    const float w2 = Wc[c * 4 + 2], w3 = Wc[c * 4 + 3];
    const float bcv = bc[c];
    const int tb = lt * 8;
    float uo[8], zo[8];
#pragma unroll
    for (int j = 0; j < 8; ++j) {
        const int r = tb + j;
        float acc = bcv + xs[r][lc] * w0 + xs[r + 1][lc] * w1
                        + xs[r + 2][lc] * w2 + xs[r + 3][lc] * w3;
        uo[j] = acc / (1.f + __expf(-acc));
        const float zv = zsh[r][lc];
        zo[j] = zv / (1.f + __expf(-zv));
    }
    const size_t m0 = (size_t)b * LL + t0 + tb;
    float* utp = u_t + (size_t)c * MROWS + m0;
    *(float4*)&utp[0] = make_float4(uo[0], uo[1], uo[2], uo[3]);
    *(float4*)&utp[4] = make_float4(uo[4], uo[5], uo[6], uo[7]);
    float* ztp = zs_t + (size_t)c * MROWS + m0;
    *(float4*)&ztp[0] = make_float4(zo[0], zo[1], zo[2], zo[3]);
    *(float4*)&ztp[4] = make_float4(zo[4], zo[5], zo[6], zo[7]);
}

// ---------------------------------------------------------------------------
// proj: Pt[n][m] (unchanged)
// ---------------------------------------------------------------------------
__global__ __launch_bounds__(256) void proj_gemm_t(const float* __restrict__ u_t,
                                                   const float* __restrict__ Wx,
                                                   float* __restrict__ Pt) {
    const int BKp = 64;
    __shared__ float Us[16][BKp + 1];
    __shared__ float Ws[96][BKp + 1];
    const int tid = threadIdx.x;
    const int m0 = blockIdx.x * 16;
    const int tx = tid & 31;
    const int ty = tid >> 5;
    float acc[2][3] = {{0.f, 0.f, 0.f}, {0.f, 0.f, 0.f}};

    for (int kt = 0; kt < DI; kt += BKp) {
#pragma unroll
        for (int i = 0; i < 4; ++i) {
            const int idx = tid + i * 256;
            const int mm = idx & 15;
            const int cc = idx >> 4;
            Us[mm][cc] = u_t[(size_t)(kt + cc) * MROWS + m0 + mm];
        }
#pragma unroll
        for (int i = 0; i < 6; ++i) {
            const int idx = tid + i * 256;
            const int r = idx >> 4;
            const int c4 = (idx & 15) << 2;
            float4 v = *(const float4*)&Wx[(size_t)r * DI + kt + c4];
            Ws[r][c4] = v.x; Ws[r][c4 + 1] = v.y; Ws[r][c4 + 2] = v.z; Ws[r][c4 + 3] = v.w;
        }
        __syncthreads();
#pragma unroll 8
        for (int k = 0; k < BKp; ++k) {
            const float um0 = Us[ty * 2][k];
            const float um1 = Us[ty * 2 + 1][k];
#pragma unroll
            for (int j = 0; j < 3; ++j) {
                const float w = Ws[tx + 32 * j][k];
                acc[0][j] += um0 * w;
                acc[1][j] += um1 * w;
            }
        }
        __syncthreads();
    }
#pragma unroll
    for (int i = 0; i < 2; ++i)
#pragma unroll
        for (int j = 0; j < 3; ++j)
            Pt[(size_t)(tx + 32 * j) * MROWS + m0 + ty * 2 + i] = acc[i][j];
}

// ---------------------------------------------------------------------------
// dt_t[c][m] (unchanged)
// ---------------------------------------------------------------------------
__global__ __launch_bounds__(256) void dt_gemm_t(const float* __restrict__ Pt,
                                                 const float* __restrict__ Wdt,
                                                 const float* __restrict__ bdt,
                                                 float* __restrict__ dtb_t) {
    __shared__ float ps[64][16];
    const int tid = threadIdx.x;
    const int c = blockIdx.x * 256 + tid;
    const int m0 = blockIdx.y * 16;
#pragma unroll
    for (int i = 0; i < 4; ++i) {
        const int idx = tid + 256 * i;
        const int r = idx >> 4;
        const int mm = idx & 15;
        ps[r][mm] = Pt[(size_t)r * MROWS + m0 + mm];
    }
    float w[64];
#pragma unroll
    for (int r4 = 0; r4 < 64; r4 += 4) {
        float4 v = *(const float4*)&Wdt[(size_t)c * 64 + r4];
        w[r4] = v.x; w[r4 + 1] = v.y; w[r4 + 2] = v.z; w[r4 + 3] = v.w;
    }
    const float bd = bdt[c];
    __syncthreads();
    float acc[16];
#pragma unroll
    for (int m = 0; m < 16; ++m) acc[m] = bd;
    for (int r = 0; r < 64; ++r) {
        const float wr = w[r];
        const float4 p0 = *(const float4*)&ps[r][0];
        const float4 p1 = *(const float4*)&ps[r][4];
        const float4 p2 = *(const float4*)&ps[r][8];
        const float4 p3 = *(const float4*)&ps[r][12];
        acc[0] += p0.x * wr;  acc[1] += p0.y * wr;  acc[2] += p0.z * wr;  acc[3] += p0.w * wr;
        acc[4] += p1.x * wr;  acc[5] += p1.y * wr;  acc[6] += p1.z * wr;  acc[7] += p1.w * wr;
        acc[8] += p2.x * wr;  acc[9] += p2.y * wr;  acc[10] += p2.z * wr; acc[11] += p2.w * wr;
        acc[12] += p3.x * wr; acc[13] += p3.y * wr; acc[14] += p3.z * wr; acc[15] += p3.w * wr;
    }
    float o[16];
#pragma unroll
    for (int m = 0; m < 16; ++m) {
        const float a = acc[m];
        o[m] = (a > 20.f) ? a : __logf(1.f + __expf(a));
    }
    float* dp = dtb_t + (size_t)c * MROWS + m0;
    *(float4*)&dp[0]  = make_float4(o[0], o[1], o[2], o[3]);
    *(float4*)&dp[4]  = make_float4(o[4], o[5], o[6], o[7]);
    *(float4*)&dp[8]  = make_float4(o[8], o[9], o[10], o[11]);
    *(float4*)&dp[12] = make_float4(o[12], o[13], o[14], o[15]);
}

// ---------------------------------------------------------------------------
// Selective scan + gating (unchanged)
// ---------------------------------------------------------------------------
__global__ __launch_bounds__(256) void scan_gate_t(const float* __restrict__ dtb_t,
                                                   const float* __restrict__ u_t,
                                                   const float* __restrict__ Pt,
                                                   const float* __restrict__ zs_t,
                                                   const float* __restrict__ A_log,
                                                   float* __restrict__ gated_t) {
    const int g = blockIdx.x * 256 + threadIdx.x;
    const int s = g & 15;
    const int cg = g >> 4;
    const int c = cg & (DI - 1);
    const int b = cg >> 11;
    const float Aval = -expf(A_log[c * 16 + s]);

    const size_t mb = (size_t)b * LL;
    const float* dtp = dtb_t + (size_t)c * MROWS + mb;
    const float* up  = u_t   + (size_t)c * MROWS + mb;
    const float* zp  = zs_t  + (size_t)c * MROWS + mb;
    const float* Bp  = Pt + (size_t)(64 + s) * MROWS + mb;
    const float* Cp  = Pt + (size_t)(80 + s) * MROWS + mb;
    float* gp = gated_t + (size_t)c * MROWS + mb;

    float4 d0 = *(const float4*)(dtp);     float4 d1 = *(const float4*)(dtp + 4);
    float4 uu0 = *(const float4*)(up);     float4 uu1 = *(const float4*)(up + 4);
    float4 B0 = *(const float4*)(Bp);      float4 B1 = *(const float4*)(Bp + 4);
    float4 C0 = *(const float4*)(Cp);      float4 C1 = *(const float4*)(Cp + 4);
    float4 z0 = *(const float4*)(zp);      float4 z1 = *(const float4*)(zp + 4);

    float h = 0.f;

#define SSTEP(dtv, uv, Bv, Cv, yy) {                 \
        const float ab = __expf((dtv) * Aval);       \
        h = ab * h + ((dtv) * (Bv)) * (uv);          \
        float y_ = (Cv) * h;                         \
        y_ += __shfl_xor(y_, 1);                     \
        y_ += __shfl_xor(y_, 2);                     \
        y_ += __shfl_xor(y_, 4);                     \
        y_ += __shfl_xor(y_, 8);                     \
        yy = y_; }

    for (int t0 = 0; t0 < LL; t0 += 8) {
        const int nt = (t0 + 8 < LL) ? (t0 + 8) : 0;
        float4 nd0 = *(const float4*)(dtp + nt);  float4 nd1 = *(const float4*)(dtp + nt + 4);
        float4 nu0 = *(const float4*)(up + nt);   float4 nu1 = *(const float4*)(up + nt + 4);
        float4 nB0 = *(const float4*)(Bp + nt);   float4 nB1 = *(const float4*)(Bp + nt + 4);
        float4 nC0 = *(const float4*)(Cp + nt);   float4 nC1 = *(const float4*)(Cp + nt + 4);
        float4 nz0 = *(const float4*)(zp + nt);   float4 nz1 = *(const float4*)(zp + nt + 4);

        float y0, y1, y2, y3, y4, y5, y6, y7;
        SSTEP(d0.x, uu0.x, B0.x, C0.x, y0);
        SSTEP(d0.y, uu0.y, B0.y, C0.y, y1);
        SSTEP(d0.z, uu0.z, B0.z, C0.z, y2);
        SSTEP(d0.w, uu0.w, B0.w, C0.w, y3);
        SSTEP(d1.x, uu1.x, B1.x, C1.x, y4);
        SSTEP(d1.y, uu1.y, B1.y, C1.y, y5);
        SSTEP(d1.z, uu1.z, B1.z, C1.z, y6);
        SSTEP(d1.w, uu1.w, B1.w, C1.w, y7);

        if (s == 0) {
            *(float4*)(gp + t0)     = make_float4(y0 * z0.x, y1 * z0.y, y2 * z0.z, y3 * z0.w);
            *(float4*)(gp + t0 + 4) = make_float4(y4 * z1.x, y5 * z1.y, y6 * z1.z, y7 * z1.w);
        }
        d0 = nd0; d1 = nd1; uu0 = nu0; uu1 = nu1;
        B0 = nB0; B1 = nB1; C0 = nC0; C1 = nC1;
        z0 = nz0; z1 = nz1;
    }
#undef SSTEP
}

// ---------------------------------------------------------------------------
// Workspace layout (floats), max extent 21,168,128 (proven footprint).
// Phase-aliased; all regions below are multiples of 16 B from base.
//   xz      [0,        8388608)   then gated_t [0,4194304), P2_1 [4194304,6291456)
//   A1s/A2s/A3s  [8388608,11534336)  (bf16 halves) -> dead after GEMM1
//   B1s/B2s/B3s  [11534336,17825792) -> dead after GEMM1
//   u_t [8388608,12582912), zs_t [12582912,16777216)  (after GEMM1)
//   Pt [16777216,16973824), dtb_t [16973824,21168128)
//   G1s/G2s/G3s [8388608,14680064), Wo1s..3s [14680064,17825792) (after scan)
// ---------------------------------------------------------------------------
extern "C" void kernel_launch(void* const* d_in, const int* in_sizes, int n_in,
                              void* d_out, int out_size, void* d_ws, size_t ws_size,
                              hipStream_t stream) {
    const float* inputs = (const float*)d_in[0];
    const float* W_in   = (const float*)d_in[1];
    const float* W_conv = (const float*)d_in[2];
    const float* b_conv = (const float*)d_in[3];
    const float* W_x    = (const float*)d_in[4];
    const float* W_dt   = (const float*)d_in[5];
    const float* b_dt   = (const float*)d_in[6];
    const float* A_log  = (const float*)d_in[7];
    const float* W_out  = (const float*)d_in[8];
    float* out = (float*)d_out;

    float* ws = (float*)d_ws;
    float* xz      = ws;
    float* gated_t = ws;
    float* P2_1    = ws + 4194304;
    unsigned short* A1s = (unsigned short*)(ws + 8388608);
    unsigned short* A2s = (unsigned short*)(ws + 9437184);
    unsigned short* A3s = (unsigned short*)(ws + 10485760);
    unsigned short* B1s = (unsigned short*)(ws + 11534336);
    unsigned short* B2s = (unsigned short*)(ws + 13631488);
    unsigned short* B3s = (unsigned short*)(ws + 15728640);
    float* u_t     = ws + 8388608;
    float* zs_t    = ws + 12582912;
    float* Pt      = ws + 16777216;
    float* dtb_t   = ws + 16973824;
    unsigned short* G1s  = (unsigned short*)(ws + 8388608);
    unsigned short* G2s  = (unsigned short*)(ws + 10485760);
    unsigned short* G3s  = (unsigned short*)(ws + 12582912);
    unsigned short* Wo1s = (unsigned short*)(ws + 14680064);
    unsigned short* Wo2s = (unsigned short*)(ws + 15728640);
    unsigned short* Wo3s = (unsigned short*)(ws + 16777216);

    // 0a) split inputs (2048x1024) and W_in (4096x1024) into bf16 triples
    split3<<<2048, 256, 0, stream>>>((const float4*)inputs, (ushort4*)A1s,
                                     (ushort4*)A2s, (ushort4*)A3s, 524288);
    split3<<<2048, 256, 0, stream>>>((const float4*)W_in, (ushort4*)B1s,
                                     (ushort4*)B2s, (ushort4*)B3s, 1048576);
    // 1) xz = inputs @ W_in^T via split-bf16 MFMA  (M=2048,N=4096,K=1024)
    gemm_mfma_split<<<dim3(32, 16, 1), 256, 0, stream>>>(
        A1s, A2s, A3s, B1s, B2s, B3s, xz, xz, MROWS, 2 * DI, DD, DD);
    // 2) u_t, zs_t  (overwrites dead A/B splits)
    conv_silu_t<<<dim3(DI / CCC, LL / CTT, BB), 256, 0, stream>>>(xz, W_conv, b_conv, u_t, zs_t);
    // 3) Pt = (u @ W_x^T)^T
    proj_gemm_t<<<dim3(MROWS / 16), 256, 0, stream>>>(u_t, W_x, Pt);
    // 4) dtb_t
    dt_gemm_t<<<dim3(DI / 256, MROWS / 16), 256, 0, stream>>>(Pt, W_dt, b_dt, dtb_t);
    // 5) scan + gate -> gated_t [K=2048][M=2048] (k-major)
    scan_gate_t<<<dim3(BB * DI * SS / 256), 256, 0, stream>>>(dtb_t, u_t, Pt, zs_t, A_log, gated_t);
    // 6a) transpose+split gated -> G[m][k] bf16 triple (overwrites dead u_t/zs_t)
    split3_t<<<dim3(32, 32), 256, 0, stream>>>(gated_t, G1s, G2s, G3s);
    // 6b) split W_out (1024x2048) -> Wo triple (overwrites dead Pt/dtb head)
    split3<<<2048, 256, 0, stream>>>((const float4*)W_out, (ushort4*)Wo1s,
                                     (ushort4*)Wo2s, (ushort4*)Wo3s, 524288);
    // 7) out = gated @ W_out^T via split-bf16 MFMA, split-K=2
    //    z=0 -> out (K 0..1023), z=1 -> P2_1 (K 1024..2047)
    gemm_mfma_split<<<dim3(8, 16, 2), 256, 0, stream>>>(
        G1s, G2s, G3s, Wo1s, Wo2s, Wo3s, out, P2_1, MROWS, DD, DI, DI / 2);
    // 7b) out += P2_1
    reduce_add_inplace<<<1024, 256, 0, stream>>>((float4*)out, (const float4*)P2_1, 524288);
}